// Round 9
// baseline (209.957 us; speedup 1.0000x reference)
//
#include <hip/hip_runtime.h>
#include <hip/hip_bf16.h>
#include <math.h>

namespace {

typedef short short8 __attribute__((ext_vector_type(8)));
typedef float floatx4 __attribute__((ext_vector_type(4)));
typedef unsigned short ushort4v __attribute__((ext_vector_type(4)));
typedef unsigned short ushort8v __attribute__((ext_vector_type(8)));

__device__ __forceinline__ unsigned short f2bf(float x) {
    union { float f; unsigned u; } a; a.f = x;
    unsigned r = a.u + 0x7fff + ((a.u >> 16) & 1);   // RTNE
    return (unsigned short)(r >> 16);
}
__device__ __forceinline__ float bf2f(unsigned short h) {
    union { unsigned u; float f; } a; a.u = ((unsigned)h) << 16;
    return a.f;
}
__device__ __forceinline__ unsigned f2h(float x) {
    _Float16 h = (_Float16)x;
    unsigned short u; __builtin_memcpy(&u, &h, 2);
    return u;
}
__device__ __forceinline__ float h2f(unsigned u) {
    unsigned short us = (unsigned short)u;
    _Float16 h; __builtin_memcpy(&h, &us, 2);
    return (float)h;
}

// ============================== shared pieces ===============================
__device__ __forceinline__ void transp_tile(
    const float* __restrict__ in, unsigned short* __restrict__ out,
    int C, int P, int bs, int pBase, int cBase, int tid, float (*tile)[33])
{
    int tx = tid & 31;
    int ty = tid >> 5;
    const float* ip = in + ((size_t)bs * C + cBase) * P + pBase;
    #pragma unroll
    for (int r = 0; r < 32; r += 8)
        tile[ty + r][tx] = ip[(size_t)(ty + r) * P + tx];
    __syncthreads();
    unsigned short* op = out + ((size_t)bs * P + pBase) * C + cBase;
    #pragma unroll
    for (int r = 0; r < 32; r += 8)
        op[(size_t)(ty + r) * C + tx] = f2bf(tile[tx][ty + r]);
}

__device__ __forceinline__ void coord_prep(
    const float* __restrict__ coords, uint4* __restrict__ table, int Wd, int idx)
{
    float2 g = ((const float2*)coords)[idx];
    uint4 e;
    bool valid = (g.x >= -1.f) && (g.x <= 1.f) && (g.y >= -1.f) && (g.y <= 1.f);
    if (!valid) {
        e.x = 0xFFFFFFFFu; e.y = 0u; e.z = 0u; e.w = 0u;
    } else {
        float ix = (g.x + 1.f) * 0.5f * (float)(Wd - 1);
        float iy = (g.y + 1.f) * 0.5f * (float)(Wd - 1);
        float x0f = floorf(ix), y0f = floorf(iy);
        float wx = ix - x0f, wy = iy - y0f;
        int x0 = min(max((int)x0f, 0), Wd - 1);
        int x1 = min(x0 + 1, Wd - 1);
        int y0 = min(max((int)y0f, 0), Wd - 1);
        int y1 = min(y0 + 1, Wd - 1);
        unsigned p00 = y0 * Wd + x0, p01 = y0 * Wd + x1;
        unsigned p10 = y1 * Wd + x0, p11 = y1 * Wd + x1;
        e.x = p00 | (p01 << 16);
        e.y = p10 | (p11 << 16);
        e.z = f2h((1.f - wx) * (1.f - wy)) | (f2h(wx * (1.f - wy)) << 16);
        e.w = f2h((1.f - wx) * wy)         | (f2h(wx * wy) << 16);
    }
    table[idx] = e;
}

__device__ __forceinline__ void cvt_seg(
    const float* __restrict__ in, unsigned short* __restrict__ out, int local, int tid)
{
    long idx = ((long)local * 256 + tid) * 4;
    float4 v = *reinterpret_cast<const float4*>(in + idx);
    ushort4 u;
    u.x = f2bf(v.x); u.y = f2bf(v.y); u.z = f2bf(v.z); u.w = f2bf(v.w);
    *reinterpret_cast<ushort4*>(out + idx) = u;
}

// sampler: 1 m per wave-chunk, 4 ch/lane, 8 B gathers, corner table.
__device__ __forceinline__ void sample_core(
    const unsigned short* __restrict__ featT, const uint4* __restrict__ table,
    unsigned short* __restrict__ vout,
    int P, int M, int C, int logM, int b, int m, int chunk, int lane)
{
    int c = chunk * 256 + lane * 4;
    unsigned short outv[16];
    #pragma unroll
    for (int y = 0; y < 4; ++y) {
        float bst0 = -3.4e38f, bst1 = -3.4e38f, bst2 = -3.4e38f, bst3 = -3.4e38f;
        bool anyinv = false;
        #pragma unroll
        for (int s = 0; s < 4; ++s) {
            int bs = b * 4 + s;
            uint4 e = table[(((size_t)bs * 4 + y) << logM) + m];
            if ((e.x & 0xffffu) == 0xffffu) { anyinv = true; continue; }
            unsigned p00 = e.x & 0xffffu, p01 = e.x >> 16;
            unsigned p10 = e.y & 0xffffu, p11 = e.y >> 16;
            float w00 = h2f(e.z & 0xffffu), w01 = h2f(e.z >> 16);
            float w10 = h2f(e.w & 0xffffu), w11 = h2f(e.w >> 16);
            const unsigned short* fp = featT + (size_t)bs * P * C + c;
            ushort4v u00 = *reinterpret_cast<const ushort4v*>(fp + (size_t)p00 * C);
            ushort4v u01 = *reinterpret_cast<const ushort4v*>(fp + (size_t)p01 * C);
            ushort4v u10 = *reinterpret_cast<const ushort4v*>(fp + (size_t)p10 * C);
            ushort4v u11 = *reinterpret_cast<const ushort4v*>(fp + (size_t)p11 * C);
            bst0 = fmaxf(bst0, bf2f(u00[0]) * w00 + bf2f(u01[0]) * w01 + bf2f(u10[0]) * w10 + bf2f(u11[0]) * w11);
            bst1 = fmaxf(bst1, bf2f(u00[1]) * w00 + bf2f(u01[1]) * w01 + bf2f(u10[1]) * w10 + bf2f(u11[1]) * w11);
            bst2 = fmaxf(bst2, bf2f(u00[2]) * w00 + bf2f(u01[2]) * w01 + bf2f(u10[2]) * w10 + bf2f(u11[2]) * w11);
            bst3 = fmaxf(bst3, bf2f(u00[3]) * w00 + bf2f(u01[3]) * w01 + bf2f(u10[3]) * w10 + bf2f(u11[3]) * w11);
        }
        if (anyinv) {
            bst0 = fmaxf(bst0, 0.f); bst1 = fmaxf(bst1, 0.f);
            bst2 = fmaxf(bst2, 0.f); bst3 = fmaxf(bst3, 0.f);
        }
        outv[0 * 4 + y] = f2bf(bst0);
        outv[1 * 4 + y] = f2bf(bst1);
        outv[2 * 4 + y] = f2bf(bst2);
        outv[3 * 4 + y] = f2bf(bst3);
    }
    size_t base = (((size_t)b << logM) + m) * ((size_t)C * 4) + (size_t)chunk * 1024 + lane * 16;
    ushort8v o0, o1;
    #pragma unroll
    for (int t = 0; t < 8; ++t) { o0[t] = outv[t]; o1[t] = outv[8 + t]; }
    *reinterpret_cast<ushort8v*>(vout + base)     = o0;
    *reinterpret_cast<ushort8v*>(vout + base + 8) = o1;
}

#define GLOAD(s, it) do { \
    w##s##a = *reinterpret_cast<const float4*>(Wp + (size_t)row0 * K + (it) * 64 + kc); \
    w##s##b = *reinterpret_cast<const float4*>(Wp + (size_t)(row0 + 32) * K + (it) * 64 + kc); \
    v##s##a = *reinterpret_cast<const float4*>(Vp + (size_t)row0 * K + (it) * 64 + kc); \
    v##s##b = *reinterpret_cast<const float4*>(Vp + (size_t)(row0 + 32) * K + (it) * 64 + kc); \
} while (0)

#define LSTORE(s, buf) do { \
    *reinterpret_cast<float4*>(&As[buf][row0 * 72 + kc]) = w##s##a; \
    *reinterpret_cast<float4*>(&As[buf][(row0 + 32) * 72 + kc]) = w##s##b; \
    *reinterpret_cast<float4*>(&Bs[buf][row0 * 72 + kc]) = v##s##a; \
    *reinterpret_cast<float4*>(&Bs[buf][(row0 + 32) * 72 + kc]) = v##s##b; \
} while (0)

#define MFMA_STEP(buf) do { \
    _Pragma("unroll") \
    for (int kss = 0; kss < 64; kss += 32) { \
        short8 af0 = *reinterpret_cast<const short8*>(&As[buf][(wo + lr) * 72 + kss + quad * 8]); \
        short8 af1 = *reinterpret_cast<const short8*>(&As[buf][(wo + 16 + lr) * 72 + kss + quad * 8]); \
        short8 bf0 = *reinterpret_cast<const short8*>(&Bs[buf][(wm + lr) * 72 + kss + quad * 8]); \
        short8 bf1 = *reinterpret_cast<const short8*>(&Bs[buf][(wm + 16 + lr) * 72 + kss + quad * 8]); \
        acc[0][0] = __builtin_amdgcn_mfma_f32_16x16x32_bf16(af0, bf0, acc[0][0], 0, 0, 0); \
        acc[0][1] = __builtin_amdgcn_mfma_f32_16x16x32_bf16(af0, bf1, acc[0][1], 0, 0, 0); \
        acc[1][0] = __builtin_amdgcn_mfma_f32_16x16x32_bf16(af1, bf0, acc[1][0], 0, 0, 0); \
        acc[1][1] = __builtin_amdgcn_mfma_f32_16x16x32_bf16(af1, bf1, acc[1][1], 0, 0, 0); \
    } \
} while (0)

__device__ __forceinline__ void gemm_tile(
    const unsigned short* __restrict__ Wb, const unsigned short* __restrict__ Vb,
    const float* __restrict__ bias, float* __restrict__ out, float* __restrict__ partial,
    int N, int K, int M, int kSplit, int local, int logMt, int logNt,
    int tid, unsigned short (*As)[64 * 72], unsigned short (*Bs)[64 * 72])
{
    const int mTile = local & ((1 << logMt) - 1);
    const int rest  = local >> logMt;
    const int oTile = rest & ((1 << logNt) - 1);
    const int z     = rest >> logNt;
    const int b = z & 1;
    const int ks = z >> 1;
    const int Kspan = K / kSplit;
    const int nIter = Kspan >> 6;

    const int mBase = mTile * 64;
    const int oBase = oTile * 64;
    const int lane = tid & 63;
    const int wave = tid >> 6;
    const int wo = (wave >> 1) * 32;
    const int wm = (wave & 1) * 32;
    const int quad = lane >> 4;
    const int lr = lane & 15;
    const int row0 = tid >> 3;
    const int kc = (tid & 7) * 8;

    const unsigned short* Wp = Wb + (size_t)oBase * K + ks * Kspan;
    const unsigned short* Vp = Vb + ((size_t)b * M + mBase) * K + ks * Kspan;

    floatx4 acc[2][2] = {};
    float4 w0a, w0b, v0a, v0b;
    float4 w1a, w1b, v1a, v1b;

    GLOAD(0, 0);
    LSTORE(0, 0);
    GLOAD(1, 1);
    __syncthreads();

    for (int it = 0; it < nIter; it += 2) {
        MFMA_STEP(0);
        LSTORE(1, 1);
        if (it + 2 < nIter) GLOAD(0, it + 2);
        __syncthreads();
        MFMA_STEP(1);
        if (it + 2 < nIter) {
            LSTORE(0, 0);
            if (it + 3 < nIter) GLOAD(1, it + 3);
            __syncthreads();
        }
    }

    if (kSplit == 1) {
        #pragma unroll
        for (int i = 0; i < 2; ++i)
            #pragma unroll
            for (int r = 0; r < 4; ++r) {
                int o = oBase + wo + i * 16 + quad * 4 + r;
                float bi = bias[o];
                #pragma unroll
                for (int j = 0; j < 2; ++j) {
                    int m = mBase + wm + j * 16 + lr;
                    float x = acc[i][j][r] + bi;
                    out[((size_t)b * N + o) * M + m] = x / (1.f + __expf(-x));
                }
            }
    } else {
        float* pp = partial + (size_t)z * N * M;
        #pragma unroll
        for (int i = 0; i < 2; ++i)
            #pragma unroll
            for (int r = 0; r < 4; ++r) {
                int o = oBase + wo + i * 16 + quad * 4 + r;
                #pragma unroll
                for (int j = 0; j < 2; ++j) {
                    int m = mBase + wm + j * 16 + lr;
                    pp[(size_t)o * M + m] = acc[i][j][r];
                }
            }
    }
}

// ===================== L1: prep for scale 2 (+mask) =========================
// T2 [0,8192)  CVTw2 [8192,8448)  CP2 [8448,8960)  MASK [8960,9088)
__global__ __launch_bounds__(256) void prep_s2(
    const float* __restrict__ x3, unsigned short* __restrict__ f2,
    const float* __restrict__ w2, unsigned short* __restrict__ o2,
    const float* __restrict__ c2, uint4* __restrict__ t2,
    float* __restrict__ mask)
{
    __shared__ float tile[32][33];
    int bid = blockIdx.x;
    int tid = threadIdx.x;
    if (bid < 8192) {
        int bs = bid >> 10, r = bid & 1023;
        transp_tile(x3, f2, 256, 4096, bs, (r & 127) * 32, (r >> 7) * 32, tid, tile);
    } else if (bid < 8448) {
        cvt_seg(w2, o2, bid - 8192, tid);
    } else if (bid < 8960) {
        coord_prep(c2, t2, 64, (bid - 8448) * 256 + tid);
    } else {
        int idx = (bid - 8960) * 256 + tid;          // [0, 32768)
        int n = idx & 16383;
        int b = idx >> 14;
        float best = 0.f;
        #pragma unroll
        for (int s = 0; s < 4; ++s) {
            float2 g = ((const float2*)c2)[(size_t)(b * 4 + s) * 16384 + n];
            bool valid = (g.x >= -1.f) && (g.x <= 1.f) && (g.y >= -1.f) && (g.y <= 1.f);
            if (valid) best = 1.f;
        }
        mask[idx] = best;
    }
}

// ===================== L2: sample s2 ⊕ prep s4/s8 ==========================
// S2 [0,2048)  T4 [2048,6144)  T8 [6144,8192)  CVTw4 [8192,9216)
// CVTw8 [9216,13312)  CP4 [13312,13440)  CP8 [13440,13472)
__global__ __launch_bounds__(256) void samp2_prep48(
    const unsigned short* __restrict__ f2, const uint4* __restrict__ t2,
    unsigned short* __restrict__ v2,
    const float* __restrict__ x4, const float* __restrict__ x5,
    unsigned short* __restrict__ f4, unsigned short* __restrict__ f8,
    const float* __restrict__ w4, const float* __restrict__ w8,
    unsigned short* __restrict__ o4, unsigned short* __restrict__ o8,
    const float* __restrict__ c4, const float* __restrict__ c8,
    uint4* __restrict__ t4, uint4* __restrict__ t8)
{
    __shared__ float tile[32][33];
    int bid = blockIdx.x;
    int tid = threadIdx.x;
    int w = tid >> 6;
    int lane = tid & 63;
    if (bid < 2048) {                 // sample s2: 4 m/block, b = low bit
        sample_core(f2, t2, v2, 4096, 4096, 256, 12,
                    bid & 1, (bid >> 1) * 4 + w, 0, lane);
    } else if (bid < 6144) {
        int local = bid - 2048;
        int bs = local >> 9, r = local & 511;
        transp_tile(x4, f4, 512, 1024, bs, (r & 31) * 32, (r >> 5) * 32, tid, tile);
    } else if (bid < 8192) {
        int local = bid - 6144;
        int bs = local >> 8, r = local & 255;
        transp_tile(x5, f8, 1024, 256, bs, (r & 7) * 32, (r >> 3) * 32, tid, tile);
    } else if (bid < 9216) {
        cvt_seg(w4, o4, bid - 8192, tid);
    } else if (bid < 13312) {
        cvt_seg(w8, o8, bid - 9216, tid);
    } else if (bid < 13440) {
        coord_prep(c4, t4, 32, (bid - 13312) * 256 + tid);
    } else {
        coord_prep(c8, t8, 16, (bid - 13440) * 256 + tid);
    }
}

// ===================== L3: sample s4/s8 ⊕ gemm s2 ==========================
// S4 [0,1024)  S8 [1024,1536)  G2 [1536,2048)
__global__ __launch_bounds__(256) void samp48_gemm2(
    const unsigned short* __restrict__ f4, const unsigned short* __restrict__ f8,
    const uint4* __restrict__ t4, const uint4* __restrict__ t8,
    unsigned short* __restrict__ v4, unsigned short* __restrict__ v8,
    const unsigned short* __restrict__ w2b, const unsigned short* __restrict__ v2,
    const float* __restrict__ b2, float* __restrict__ bev2)
{
    __shared__ __align__(16) unsigned short As[2][64 * 72];
    __shared__ __align__(16) unsigned short Bs[2][64 * 72];
    int bid = blockIdx.x;
    int tid = threadIdx.x;
    int w = tid >> 6;
    int lane = tid & 63;
    if (bid < 1024) {                 // sample s4: 2 m/block
        sample_core(f4, t4, v4, 1024, 1024, 512, 10,
                    bid & 1, (bid >> 1) * 2 + (w >> 1), w & 1, lane);
    } else if (bid < 1536) {          // sample s8: 1 m/block
        int local = bid - 1024;
        sample_core(f8, t8, v8, 256, 256, 1024, 8,
                    local & 1, local >> 1, w, lane);
    } else {                          // gemm s2, split1 + fused bias/silu
        gemm_tile(w2b, v2, b2, bev2, nullptr, 256, 1024, 4096, 1,
                  bid - 1536, 6, 2, tid, As, Bs);
    }
}

// ===================== L4: gemm s4/s8 (split-K) =============================
// G4 [0,1024)  G8 [1024,2048)
__global__ __launch_bounds__(256) void gemm48(
    const unsigned short* __restrict__ w4b, const unsigned short* __restrict__ w8b,
    const unsigned short* __restrict__ v4, const unsigned short* __restrict__ v8,
    float* __restrict__ part4, float* __restrict__ part8)
{
    __shared__ __align__(16) unsigned short As[2][64 * 72];
    __shared__ __align__(16) unsigned short Bs[2][64 * 72];
    int bid = blockIdx.x;
    int tid = threadIdx.x;
    if (bid < 1024)
        gemm_tile(w4b, v4, nullptr, nullptr, part4, 512, 2048, 1024, 4, bid, 4, 3, tid, As, Bs);
    else
        gemm_tile(w8b, v8, nullptr, nullptr, part8, 1024, 4096, 256, 8, bid - 1024, 2, 4, tid, As, Bs);
}

// ===================== L5: reduce + bias + silu =============================
__device__ __forceinline__ void reduce_seg(
    const float* __restrict__ partial, const float* __restrict__ bias,
    float* __restrict__ out, int N, int M, int kSplit, size_t idx)
{
    int m4 = M >> 2;
    int mi = (int)(idx % m4);
    int o  = (int)((idx / m4) % N);
    int b  = (int)(idx / ((size_t)m4 * N));
    size_t base = ((size_t)b * N + o) * M + (size_t)mi * 4;
    size_t stride = (size_t)2 * N * M;
    float4 s = *reinterpret_cast<const float4*>(partial + base);
    for (int k = 1; k < kSplit; ++k) {
        float4 t = *reinterpret_cast<const float4*>(partial + base + (size_t)k * stride);
        s.x += t.x; s.y += t.y; s.z += t.z; s.w += t.w;
    }
    float bi = bias[o];
    float xs[4] = {s.x + bi, s.y + bi, s.z + bi, s.w + bi};
    float4 r;
    r.x = xs[0] / (1.f + __expf(-xs[0]));
    r.y = xs[1] / (1.f + __expf(-xs[1]));
    r.z = xs[2] / (1.f + __expf(-xs[2]));
    r.w = xs[3] / (1.f + __expf(-xs[3]));
    *reinterpret_cast<float4*>(out + base) = r;
}

__global__ __launch_bounds__(256) void reduce_all(
    const float* __restrict__ part4, const float* __restrict__ b4, float* __restrict__ bev4,
    const float* __restrict__ part8, const float* __restrict__ b8, float* __restrict__ bev8)
{
    int bid = blockIdx.x;
    int tid = threadIdx.x;
    if (bid < 1024)
        reduce_seg(part4, b4, bev4, 512, 1024, 4, (size_t)bid * 256 + tid);
    else
        reduce_seg(part8, b8, bev8, 1024, 256, 8, (size_t)(bid - 1024) * 256 + tid);
}

} // namespace

extern "C" void kernel_launch(void* const* d_in, const int* in_sizes, int n_in,
                              void* d_out, int out_size, void* d_ws, size_t ws_size,
                              hipStream_t stream)
{
    const float* x3 = (const float*)d_in[0];
    const float* x4 = (const float*)d_in[1];
    const float* x5 = (const float*)d_in[2];
    const float* c2 = (const float*)d_in[3];
    const float* c4 = (const float*)d_in[4];
    const float* c8 = (const float*)d_in[5];
    const float* w2 = (const float*)d_in[6];
    const float* b2 = (const float*)d_in[7];
    const float* w4 = (const float*)d_in[8];
    const float* b4 = (const float*)d_in[9];
    const float* w8 = (const float*)d_in[10];
    const float* b8 = (const float*)d_in[11];

    float* out  = (float*)d_out;
    float* bev2 = out;
    float* bev4 = bev2 + (long)2 * 256 * 64 * 64;
    float* bev8 = bev4 + (long)2 * 512 * 32 * 32;
    float* mask = bev8 + (long)2 * 1024 * 16 * 16;

    // ws layout (MiB offsets):
    //   f2 0(16) f4 16(8) f8 24(4) | v2 28(16) v4 44(8) v8 52(4)
    //   w2bf 56(0.5) w4bf 57(2) w8bf 59(8) | part4 68(16) part8 84(16)
    //   t2 100(2) t4 102(0.5) t8 102.5(0.125)
    char* ws = (char*)d_ws;
    unsigned short* f2v  = (unsigned short*)(ws);
    unsigned short* f4v  = (unsigned short*)(ws + (16L << 20));
    unsigned short* f8v  = (unsigned short*)(ws + (24L << 20));
    unsigned short* v2v  = (unsigned short*)(ws + (28L << 20));
    unsigned short* v4v  = (unsigned short*)(ws + (44L << 20));
    unsigned short* v8v  = (unsigned short*)(ws + (52L << 20));
    unsigned short* w2bf = (unsigned short*)(ws + (56L << 20));
    unsigned short* w4bf = (unsigned short*)(ws + (57L << 20));
    unsigned short* w8bf = (unsigned short*)(ws + (59L << 20));
    float*          part4 = (float*)(ws + (68L << 20));
    float*          part8 = (float*)(ws + (84L << 20));
    uint4*          t2v   = (uint4*)(ws + (100L << 20));
    uint4*          t4v   = (uint4*)(ws + (102L << 20));
    uint4*          t8v   = (uint4*)(ws + (102L << 20) + (1L << 19));

    prep_s2<<<dim3(9088), 256, 0, stream>>>(x3, f2v, w2, w2bf, c2, t2v, mask);
    samp2_prep48<<<dim3(13472), 256, 0, stream>>>(
        f2v, t2v, v2v, x4, x5, f4v, f8v, w4, w8, w4bf, w8bf, c4, c8, t4v, t8v);
    samp48_gemm2<<<dim3(2048), 256, 0, stream>>>(
        f4v, f8v, t4v, t8v, v4v, v8v, w2bf, v2v, b2, bev2);
    gemm48<<<dim3(2048), 256, 0, stream>>>(w4bf, w8bf, v4v, v8v, part4, part8);
    reduce_all<<<dim3(1536), 256, 0, stream>>>(part4, b4, bev4, part8, b8, bev8);
}

// Round 10
// 197.354 us; speedup vs baseline: 1.0639x; 1.0639x over previous
//
#include <hip/hip_runtime.h>
#include <hip/hip_bf16.h>
#include <math.h>

namespace {

typedef short short8 __attribute__((ext_vector_type(8)));
typedef float floatx4 __attribute__((ext_vector_type(4)));
typedef unsigned short ushort4v __attribute__((ext_vector_type(4)));
typedef unsigned short ushort8v __attribute__((ext_vector_type(8)));

__device__ __forceinline__ unsigned short f2bf(float x) {
    union { float f; unsigned u; } a; a.f = x;
    unsigned r = a.u + 0x7fff + ((a.u >> 16) & 1);   // RTNE
    return (unsigned short)(r >> 16);
}
__device__ __forceinline__ float bf2f(unsigned short h) {
    union { unsigned u; float f; } a; a.u = ((unsigned)h) << 16;
    return a.f;
}
__device__ __forceinline__ unsigned f2h(float x) {
    _Float16 h = (_Float16)x;
    unsigned short u; __builtin_memcpy(&u, &h, 2);
    return u;
}
__device__ __forceinline__ float h2f(unsigned u) {
    unsigned short us = (unsigned short)u;
    _Float16 h; __builtin_memcpy(&h, &us, 2);
    return (float)h;
}

// ============================== prep pieces =================================
__device__ __forceinline__ void transp_tile(
    const float* __restrict__ in, unsigned short* __restrict__ out,
    int C, int P, int bs, int pBase, int cBase, int tid, float (*tile)[33])
{
    int tx = tid & 31;
    int ty = tid >> 5;
    const float* ip = in + ((size_t)bs * C + cBase) * P + pBase;
    #pragma unroll
    for (int r = 0; r < 32; r += 8)
        tile[ty + r][tx] = ip[(size_t)(ty + r) * P + tx];
    __syncthreads();
    unsigned short* op = out + ((size_t)bs * P + pBase) * C + cBase;
    #pragma unroll
    for (int r = 0; r < 32; r += 8)
        op[(size_t)(ty + r) * C + tx] = f2bf(tile[tx][ty + r]);
}

__device__ __forceinline__ void coord_prep(
    const float* __restrict__ coords, uint4* __restrict__ table, int Wd, int idx)
{
    float2 g = ((const float2*)coords)[idx];
    uint4 e;
    bool valid = (g.x >= -1.f) && (g.x <= 1.f) && (g.y >= -1.f) && (g.y <= 1.f);
    if (!valid) {
        e.x = 0xFFFFFFFFu; e.y = 0u; e.z = 0u; e.w = 0u;
    } else {
        float ix = (g.x + 1.f) * 0.5f * (float)(Wd - 1);
        float iy = (g.y + 1.f) * 0.5f * (float)(Wd - 1);
        float x0f = floorf(ix), y0f = floorf(iy);
        float wx = ix - x0f, wy = iy - y0f;
        int x0 = min(max((int)x0f, 0), Wd - 1);
        int x1 = min(x0 + 1, Wd - 1);
        int y0 = min(max((int)y0f, 0), Wd - 1);
        int y1 = min(y0 + 1, Wd - 1);
        unsigned p00 = y0 * Wd + x0, p01 = y0 * Wd + x1;
        unsigned p10 = y1 * Wd + x0, p11 = y1 * Wd + x1;
        e.x = p00 | (p01 << 16);
        e.y = p10 | (p11 << 16);
        e.z = f2h((1.f - wx) * (1.f - wy)) | (f2h(wx * (1.f - wy)) << 16);
        e.w = f2h((1.f - wx) * wy)         | (f2h(wx * wy) << 16);
    }
    table[idx] = e;
}

__device__ __forceinline__ void cvt_seg(
    const float* __restrict__ in, unsigned short* __restrict__ out, int local, int tid)
{
    long idx = ((long)local * 256 + tid) * 4;
    float4 v = *reinterpret_cast<const float4*>(in + idx);
    ushort4 u;
    u.x = f2bf(v.x); u.y = f2bf(v.y); u.z = f2bf(v.z); u.w = f2bf(v.w);
    *reinterpret_cast<ushort4*>(out + idx) = u;
}

// block ranges:
//  T2 [0,8192) T4 [8192,12288) T8 [12288,14336)
//  CVT [14336,19712)  CP2 [19712,20224) CP4 [20224,20352) CP8 [20352,20384)
//  MASK [20384,20512)
__global__ __launch_bounds__(256) void prep_all(
    const float* __restrict__ x3, const float* __restrict__ x4, const float* __restrict__ x5,
    unsigned short* __restrict__ f2, unsigned short* __restrict__ f4, unsigned short* __restrict__ f8,
    const float* __restrict__ w2, const float* __restrict__ w4, const float* __restrict__ w8,
    unsigned short* __restrict__ o2, unsigned short* __restrict__ o4, unsigned short* __restrict__ o8,
    const float* __restrict__ c2, const float* __restrict__ c4, const float* __restrict__ c8,
    uint4* __restrict__ t2, uint4* __restrict__ t4, uint4* __restrict__ t8,
    float* __restrict__ mask)
{
    __shared__ float tile[32][33];
    int bid = blockIdx.x;
    int tid = threadIdx.x;
    if (bid < 8192) {
        int bs = bid >> 10, r = bid & 1023;
        transp_tile(x3, f2, 256, 4096, bs, (r & 127) * 32, (r >> 7) * 32, tid, tile);
    } else if (bid < 12288) {
        int local = bid - 8192;
        int bs = local >> 9, r = local & 511;
        transp_tile(x4, f4, 512, 1024, bs, (r & 31) * 32, (r >> 5) * 32, tid, tile);
    } else if (bid < 14336) {
        int local = bid - 12288;
        int bs = local >> 8, r = local & 255;
        transp_tile(x5, f8, 1024, 256, bs, (r & 7) * 32, (r >> 3) * 32, tid, tile);
    } else if (bid < 19712) {
        int local = bid - 14336;
        const float* in; unsigned short* out;
        if (local < 256)       { in = w2; out = o2; }
        else if (local < 1280) { in = w4; out = o4; local -= 256; }
        else                   { in = w8; out = o8; local -= 1280; }
        cvt_seg(in, out, local, tid);
    } else if (bid < 20224) {
        coord_prep(c2, t2, 64, (bid - 19712) * 256 + tid);
    } else if (bid < 20352) {
        coord_prep(c4, t4, 32, (bid - 20224) * 256 + tid);
    } else if (bid < 20384) {
        coord_prep(c8, t8, 16, (bid - 20352) * 256 + tid);
    } else {
        int idx = (bid - 20384) * 256 + tid;        // [0, 32768)
        int n = idx & 16383;
        int b = idx >> 14;
        float best = 0.f;
        #pragma unroll
        for (int s = 0; s < 4; ++s) {
            float2 g = ((const float2*)c2)[(size_t)(b * 4 + s) * 16384 + n];
            bool valid = (g.x >= -1.f) && (g.x <= 1.f) && (g.y >= -1.f) && (g.y <= 1.f);
            if (valid) best = 1.f;
        }
        mask[idx] = best;
    }
}

// ============================ sample+max ====================================
// 1 m per wave-chunk, 4 ch/lane, 8 B gathers, corner table (round-8 winner).
__device__ __forceinline__ void sample_core(
    const unsigned short* __restrict__ featT, const uint4* __restrict__ table,
    unsigned short* __restrict__ vout,
    int P, int M, int C, int logM, int b, int m, int chunk, int lane)
{
    int c = chunk * 256 + lane * 4;
    unsigned short outv[16];
    #pragma unroll
    for (int y = 0; y < 4; ++y) {
        float bst0 = -3.4e38f, bst1 = -3.4e38f, bst2 = -3.4e38f, bst3 = -3.4e38f;
        bool anyinv = false;
        #pragma unroll
        for (int s = 0; s < 4; ++s) {
            int bs = b * 4 + s;
            uint4 e = table[(((size_t)bs * 4 + y) << logM) + m];
            if ((e.x & 0xffffu) == 0xffffu) { anyinv = true; continue; }
            unsigned p00 = e.x & 0xffffu, p01 = e.x >> 16;
            unsigned p10 = e.y & 0xffffu, p11 = e.y >> 16;
            float w00 = h2f(e.z & 0xffffu), w01 = h2f(e.z >> 16);
            float w10 = h2f(e.w & 0xffffu), w11 = h2f(e.w >> 16);
            const unsigned short* fp = featT + (size_t)bs * P * C + c;
            ushort4v u00 = *reinterpret_cast<const ushort4v*>(fp + (size_t)p00 * C);
            ushort4v u01 = *reinterpret_cast<const ushort4v*>(fp + (size_t)p01 * C);
            ushort4v u10 = *reinterpret_cast<const ushort4v*>(fp + (size_t)p10 * C);
            ushort4v u11 = *reinterpret_cast<const ushort4v*>(fp + (size_t)p11 * C);
            bst0 = fmaxf(bst0, bf2f(u00[0]) * w00 + bf2f(u01[0]) * w01 + bf2f(u10[0]) * w10 + bf2f(u11[0]) * w11);
            bst1 = fmaxf(bst1, bf2f(u00[1]) * w00 + bf2f(u01[1]) * w01 + bf2f(u10[1]) * w10 + bf2f(u11[1]) * w11);
            bst2 = fmaxf(bst2, bf2f(u00[2]) * w00 + bf2f(u01[2]) * w01 + bf2f(u10[2]) * w10 + bf2f(u11[2]) * w11);
            bst3 = fmaxf(bst3, bf2f(u00[3]) * w00 + bf2f(u01[3]) * w01 + bf2f(u10[3]) * w10 + bf2f(u11[3]) * w11);
        }
        if (anyinv) {
            bst0 = fmaxf(bst0, 0.f); bst1 = fmaxf(bst1, 0.f);
            bst2 = fmaxf(bst2, 0.f); bst3 = fmaxf(bst3, 0.f);
        }
        outv[0 * 4 + y] = f2bf(bst0);
        outv[1 * 4 + y] = f2bf(bst1);
        outv[2 * 4 + y] = f2bf(bst2);
        outv[3 * 4 + y] = f2bf(bst3);
    }
    size_t base = (((size_t)b << logM) + m) * ((size_t)C * 4) + (size_t)chunk * 1024 + lane * 16;
    ushort8v o0, o1;
    #pragma unroll
    for (int t = 0; t < 8; ++t) { o0[t] = outv[t]; o1[t] = outv[8 + t]; }
    *reinterpret_cast<ushort8v*>(vout + base)     = o0;
    *reinterpret_cast<ushort8v*>(vout + base + 8) = o1;
}

// blocks: s2 [0,2048)  s4 [2048,3072)  s8 [3072,3584); b = low block bit.
__global__ __launch_bounds__(256) void sample_all(
    const unsigned short* __restrict__ f2, const unsigned short* __restrict__ f4,
    const unsigned short* __restrict__ f8,
    const uint4* __restrict__ t2, const uint4* __restrict__ t4, const uint4* __restrict__ t8,
    unsigned short* __restrict__ v2, unsigned short* __restrict__ v4,
    unsigned short* __restrict__ v8)
{
    int bid = blockIdx.x;
    int w = threadIdx.x >> 6;
    int lane = threadIdx.x & 63;
    if (bid < 2048) {
        sample_core(f2, t2, v2, 4096, 4096, 256, 12,
                    bid & 1, (bid >> 1) * 4 + w, 0, lane);
    } else if (bid < 3072) {
        int local = bid - 2048;
        sample_core(f4, t4, v4, 1024, 1024, 512, 10,
                    local & 1, (local >> 1) * 2 + (w >> 1), w & 1, lane);
    } else {
        int local = bid - 3072;
        sample_core(f8, t8, v8, 256, 256, 1024, 8,
                    local & 1, local >> 1, w, lane);
    }
}

// ============================ GEMM: 128x128 tile ============================
// 4 waves, each 64x64 acc (4x4 MFMA 16x16x32).  BK=64, single 36 KB LDS
// buffer, GLOAD(it+1) issued before MFMA(it) so staging flies under compute.
__device__ __forceinline__ void gemm_tile128(
    const unsigned short* __restrict__ Wb, const unsigned short* __restrict__ Vb,
    const float* __restrict__ bias, float* __restrict__ out, float* __restrict__ partial,
    int N, int K, int M, int kSplit, int local, int logMt, int logNt,
    int tid, unsigned short* As, unsigned short* Bs)     // each [128*72]
{
    const int mTile = local & ((1 << logMt) - 1);
    const int rest  = local >> logMt;
    const int oTile = rest & ((1 << logNt) - 1);
    const int z     = rest >> logNt;
    const int b = z & 1;
    const int ks = z >> 1;
    const int Kspan = K / kSplit;
    const int nIter = Kspan >> 6;       // 16 for all scales

    const int mBase = mTile * 128;
    const int oBase = oTile * 128;
    const int lane = tid & 63;
    const int wave = tid >> 6;
    const int wo = (wave >> 1) * 64;
    const int wm = (wave & 1) * 64;
    const int quad = lane >> 4;
    const int lr = lane & 15;
    const int row0 = tid >> 3;          // 0..31
    const int kc = (tid & 7) * 8;       // 0..56

    const unsigned short* Wp = Wb + (size_t)oBase * K + ks * Kspan;
    const unsigned short* Vp = Vb + ((size_t)b * M + mBase) * K + ks * Kspan;

    floatx4 acc[4][4] = {};
    float4 wr0, wr1, wr2, wr3, vr0, vr1, vr2, vr3;

#define GLOAD128(it) do { \
    wr0 = *reinterpret_cast<const float4*>(Wp + (size_t)(row0      ) * K + (it) * 64 + kc); \
    wr1 = *reinterpret_cast<const float4*>(Wp + (size_t)(row0 + 32 ) * K + (it) * 64 + kc); \
    wr2 = *reinterpret_cast<const float4*>(Wp + (size_t)(row0 + 64 ) * K + (it) * 64 + kc); \
    wr3 = *reinterpret_cast<const float4*>(Wp + (size_t)(row0 + 96 ) * K + (it) * 64 + kc); \
    vr0 = *reinterpret_cast<const float4*>(Vp + (size_t)(row0      ) * K + (it) * 64 + kc); \
    vr1 = *reinterpret_cast<const float4*>(Vp + (size_t)(row0 + 32 ) * K + (it) * 64 + kc); \
    vr2 = *reinterpret_cast<const float4*>(Vp + (size_t)(row0 + 64 ) * K + (it) * 64 + kc); \
    vr3 = *reinterpret_cast<const float4*>(Vp + (size_t)(row0 + 96 ) * K + (it) * 64 + kc); \
} while (0)

#define LSTORE128() do { \
    *reinterpret_cast<float4*>(&As[(row0      ) * 72 + kc]) = wr0; \
    *reinterpret_cast<float4*>(&As[(row0 + 32 ) * 72 + kc]) = wr1; \
    *reinterpret_cast<float4*>(&As[(row0 + 64 ) * 72 + kc]) = wr2; \
    *reinterpret_cast<float4*>(&As[(row0 + 96 ) * 72 + kc]) = wr3; \
    *reinterpret_cast<float4*>(&Bs[(row0      ) * 72 + kc]) = vr0; \
    *reinterpret_cast<float4*>(&Bs[(row0 + 32 ) * 72 + kc]) = vr1; \
    *reinterpret_cast<float4*>(&Bs[(row0 + 64 ) * 72 + kc]) = vr2; \
    *reinterpret_cast<float4*>(&Bs[(row0 + 96 ) * 72 + kc]) = vr3; \
} while (0)

    GLOAD128(0);
    LSTORE128();

    for (int it = 0; it < nIter; ++it) {
        __syncthreads();                     // LDS stores visible to all waves
        if (it + 1 < nIter) GLOAD128(it + 1);   // next tile flies under compute
        #pragma unroll
        for (int kss = 0; kss < 64; kss += 32) {
            short8 af[4], bf[4];
            #pragma unroll
            for (int i = 0; i < 4; ++i)
                af[i] = *reinterpret_cast<const short8*>(&As[(wo + i * 16 + lr) * 72 + kss + quad * 8]);
            #pragma unroll
            for (int j = 0; j < 4; ++j)
                bf[j] = *reinterpret_cast<const short8*>(&Bs[(wm + j * 16 + lr) * 72 + kss + quad * 8]);
            #pragma unroll
            for (int i = 0; i < 4; ++i)
                #pragma unroll
                for (int j = 0; j < 4; ++j)
                    acc[i][j] = __builtin_amdgcn_mfma_f32_16x16x32_bf16(af[i], bf[j], acc[i][j], 0, 0, 0);
        }
        __syncthreads();                     // all waves done reading buffer
        if (it + 1 < nIter) LSTORE128();
    }

    if (kSplit == 1) {
        #pragma unroll
        for (int i = 0; i < 4; ++i)
            #pragma unroll
            for (int r = 0; r < 4; ++r) {
                int o = oBase + wo + i * 16 + quad * 4 + r;
                float bi = bias[o];
                #pragma unroll
                for (int j = 0; j < 4; ++j) {
                    int m = mBase + wm + j * 16 + lr;
                    float x = acc[i][j][r] + bi;
                    out[((size_t)b * N + o) * M + m] = x / (1.f + __expf(-x));
                }
            }
    } else {
        float* pp = partial + (size_t)z * N * M;
        #pragma unroll
        for (int i = 0; i < 4; ++i)
            #pragma unroll
            for (int r = 0; r < 4; ++r) {
                int o = oBase + wo + i * 16 + quad * 4 + r;
                #pragma unroll
                for (int j = 0; j < 4; ++j) {
                    int m = mBase + wm + j * 16 + lr;
                    pp[(size_t)o * M + m] = acc[i][j][r];
                }
            }
    }
#undef GLOAD128
#undef LSTORE128
}

// blocks: s2 [0,128) split1  s4 [128,256) split2  s8 [256,384) split4
__global__ __launch_bounds__(256, 2) void gemm_all(
    const unsigned short* __restrict__ w2b, const unsigned short* __restrict__ w4b,
    const unsigned short* __restrict__ w8b,
    const unsigned short* __restrict__ v2, const unsigned short* __restrict__ v4,
    const unsigned short* __restrict__ v8,
    const float* __restrict__ b2, float* __restrict__ bev2,
    float* __restrict__ part4, float* __restrict__ part8)
{
    __shared__ __align__(16) unsigned short As[128 * 72];
    __shared__ __align__(16) unsigned short Bs[128 * 72];
    int bid = blockIdx.x;
    int tid = threadIdx.x;
    if (bid < 128)        // s2: M=4096 (32 tiles, log5), N=256 (2, log1), z=2
        gemm_tile128(w2b, v2, b2, bev2, nullptr, 256, 1024, 4096, 1, bid, 5, 1, tid, As, Bs);
    else if (bid < 256)   // s4: M=1024 (8, log3), N=512 (4, log2), z=4 (split2)
        gemm_tile128(w4b, v4, nullptr, nullptr, part4, 512, 2048, 1024, 2, bid - 128, 3, 2, tid, As, Bs);
    else                  // s8: M=256 (2, log1), N=1024 (8, log3), z=8 (split4)
        gemm_tile128(w8b, v8, nullptr, nullptr, part8, 1024, 4096, 256, 4, bid - 256, 1, 3, tid, As, Bs);
}

// ===================== reduce + bias + silu =================================
__device__ __forceinline__ void reduce_seg(
    const float* __restrict__ partial, const float* __restrict__ bias,
    float* __restrict__ out, int N, int M, int kSplit, size_t idx)
{
    int m4 = M >> 2;
    int mi = (int)(idx % m4);
    int o  = (int)((idx / m4) % N);
    int b  = (int)(idx / ((size_t)m4 * N));
    size_t base = ((size_t)b * N + o) * M + (size_t)mi * 4;
    size_t stride = (size_t)2 * N * M;
    float4 s = *reinterpret_cast<const float4*>(partial + base);
    for (int k = 1; k < kSplit; ++k) {
        float4 t = *reinterpret_cast<const float4*>(partial + base + (size_t)k * stride);
        s.x += t.x; s.y += t.y; s.z += t.z; s.w += t.w;
    }
    float bi = bias[o];
    float xs[4] = {s.x + bi, s.y + bi, s.z + bi, s.w + bi};
    float4 r;
    r.x = xs[0] / (1.f + __expf(-xs[0]));
    r.y = xs[1] / (1.f + __expf(-xs[1]));
    r.z = xs[2] / (1.f + __expf(-xs[2]));
    r.w = xs[3] / (1.f + __expf(-xs[3]));
    *reinterpret_cast<float4*>(out + base) = r;
}

// blocks: s4 [0,1024)  s8 [1024,1536)
__global__ __launch_bounds__(256) void reduce_all(
    const float* __restrict__ part4, const float* __restrict__ b4, float* __restrict__ bev4,
    const float* __restrict__ part8, const float* __restrict__ b8, float* __restrict__ bev8)
{
    int bid = blockIdx.x;
    int tid = threadIdx.x;
    if (bid < 1024)
        reduce_seg(part4, b4, bev4, 512, 1024, 2, (size_t)bid * 256 + tid);
    else
        reduce_seg(part8, b8, bev8, 1024, 256, 4, (size_t)(bid - 1024) * 256 + tid);
}

} // namespace

extern "C" void kernel_launch(void* const* d_in, const int* in_sizes, int n_in,
                              void* d_out, int out_size, void* d_ws, size_t ws_size,
                              hipStream_t stream)
{
    const float* x3 = (const float*)d_in[0];
    const float* x4 = (const float*)d_in[1];
    const float* x5 = (const float*)d_in[2];
    const float* c2 = (const float*)d_in[3];
    const float* c4 = (const float*)d_in[4];
    const float* c8 = (const float*)d_in[5];
    const float* w2 = (const float*)d_in[6];
    const float* b2 = (const float*)d_in[7];
    const float* w4 = (const float*)d_in[8];
    const float* b4 = (const float*)d_in[9];
    const float* w8 = (const float*)d_in[10];
    const float* b8 = (const float*)d_in[11];

    float* out  = (float*)d_out;
    float* bev2 = out;
    float* bev4 = bev2 + (long)2 * 256 * 64 * 64;
    float* bev8 = bev4 + (long)2 * 512 * 32 * 32;
    float* mask = bev8 + (long)2 * 1024 * 16 * 16;

    // ws layout (MiB offsets):
    //   f2 0(16) f4 16(8) f8 24(4) | v2 28(16) v4 44(8) v8 52(4)
    //   w2bf 56(0.5) w4bf 57(2) w8bf 59(8) | part4 68(8) part8 84(8)
    //   t2 100(2) t4 102(0.5) t8 102.5(0.125)
    char* ws = (char*)d_ws;
    unsigned short* f2v  = (unsigned short*)(ws);
    unsigned short* f4v  = (unsigned short*)(ws + (16L << 20));
    unsigned short* f8v  = (unsigned short*)(ws + (24L << 20));
    unsigned short* v2v  = (unsigned short*)(ws + (28L << 20));
    unsigned short* v4v  = (unsigned short*)(ws + (44L << 20));
    unsigned short* v8v  = (unsigned short*)(ws + (52L << 20));
    unsigned short* w2bf = (unsigned short*)(ws + (56L << 20));
    unsigned short* w4bf = (unsigned short*)(ws + (57L << 20));
    unsigned short* w8bf = (unsigned short*)(ws + (59L << 20));
    float*          part4 = (float*)(ws + (68L << 20));
    float*          part8 = (float*)(ws + (84L << 20));
    uint4*          t2v   = (uint4*)(ws + (100L << 20));
    uint4*          t4v   = (uint4*)(ws + (102L << 20));
    uint4*          t8v   = (uint4*)(ws + (102L << 20) + (1L << 19));

    prep_all<<<dim3(20512), 256, 0, stream>>>(
        x3, x4, x5, f2v, f4v, f8v,
        w2, w4, w8, w2bf, w4bf, w8bf,
        c2, c4, c8, t2v, t4v, t8v, mask);
    sample_all<<<dim3(3584), 256, 0, stream>>>(
        f2v, f4v, f8v, t2v, t4v, t8v, v2v, v4v, v8v);
    gemm_all<<<dim3(384), 256, 0, stream>>>(
        w2bf, w4bf, w8bf, v2v, v4v, v8v, b2, bev2, part4, part8);
    reduce_all<<<dim3(1536), 256, 0, stream>>>(
        part4, b4, bev4, part8, b8, bev8);
}